// Round 6
// baseline (1781.052 us; speedup 1.0000x reference)
//
#include <hip/hip_runtime.h>
#include <math.h>

#define WH 64
#define WIN 256
#define TT 4
#define ALPHA_C 0.1f
#define BN 64
#define KC 32
#define XS_STRIDE (KC + 4)
#define BINS 16384              // bins over [-8, 8)
#define BIN_SCALE 1024.0f       // BINS / 16
#define HG 256                  // histogram grid (partial hists)
#define SB 256                  // scan blocks

typedef unsigned short ushortT;

__device__ __forceinline__ unsigned pack_bf16(float a, float b) {
  unsigned ua = __float_as_uint(a), ub = __float_as_uint(b);
  ua = (ua + 0x7FFFu + ((ua >> 16) & 1u)) >> 16;          // RNE
  ub = ((ub + 0x7FFFu + ((ub >> 16) & 1u)) >> 16) << 16;
  return (ua & 0xFFFFu) | ub;
}
__device__ __forceinline__ float bf_lo(unsigned p) { return __uint_as_float(p << 16); }
__device__ __forceinline__ float bf_hi(unsigned p) { return __uint_as_float(p & 0xFFFF0000u); }

// ---------- encode: H = l2norm_rows(X @ W + b) + fused per-type stats partials ----------
// launch_bounds(256,4): cap VGPR at 128 -> 4 blocks/CU (was 148 VGPR -> 3).
__global__ __launch_bounds__(256, 4) void k_encode(const float* __restrict__ X,
                                                   const float* __restrict__ W,
                                                   const float* __restrict__ bias,
                                                   const int* __restrict__ nt,
                                                   float* __restrict__ H,
                                                   float* __restrict__ psum,
                                                   float* __restrict__ psq,
                                                   float* __restrict__ pcnt, int N) {
  __shared__ __align__(16) float Xs[BN * XS_STRIDE];
  __shared__ __align__(16) float Ws[KC * WH];
  __shared__ float ls[TT * WH], ls2[TT * WH];
  __shared__ float lc[TT];
  int tid = threadIdx.x;
  int tn = tid >> 4, tc = tid & 15;
  int nodeBase = blockIdx.x * BN;
  ls[tid] = 0.0f;
  ls2[tid] = 0.0f;
  if (tid < TT) lc[tid] = 0.0f;
  float acc[4][4] = {};
  for (int k0 = 0; k0 < WIN; k0 += KC) {
    __syncthreads();
    const float4* Wg4 = (const float4*)(W + (size_t)k0 * WH);
    float4* Ws4 = (float4*)Ws;
    Ws4[tid] = Wg4[tid];
    Ws4[tid + 256] = Wg4[tid + 256];
#pragma unroll
    for (int i = 0; i < 2; ++i) {
      int idx = tid + i * 256;
      int ln = idx >> 3, f4 = idx & 7;
      int node = nodeBase + ln;
      if (node < N) {
        *(float4*)&Xs[ln * XS_STRIDE + f4 * 4] =
            *(const float4*)(X + (size_t)node * WIN + k0 + f4 * 4);
      }
    }
    __syncthreads();
    for (int kk = 0; kk < KC; kk += 4) {
      float4 b0 = *(const float4*)&Ws[(kk + 0) * WH + tc * 4];
      float4 b1 = *(const float4*)&Ws[(kk + 1) * WH + tc * 4];
      float4 b2 = *(const float4*)&Ws[(kk + 2) * WH + tc * 4];
      float4 b3 = *(const float4*)&Ws[(kk + 3) * WH + tc * 4];
#pragma unroll
      for (int i = 0; i < 4; ++i) {
        float4 a = *(const float4*)&Xs[(tn * 4 + i) * XS_STRIDE + kk];
        acc[i][0] += a.x * b0.x + a.y * b1.x + a.z * b2.x + a.w * b3.x;
        acc[i][1] += a.x * b0.y + a.y * b1.y + a.z * b2.y + a.w * b3.y;
        acc[i][2] += a.x * b0.z + a.y * b1.z + a.z * b2.z + a.w * b3.z;
        acc[i][3] += a.x * b0.w + a.y * b1.w + a.z * b2.w + a.w * b3.w;
      }
    }
  }
  float4 bv = *(const float4*)(bias + tc * 4);
#pragma unroll
  for (int i = 0; i < 4; ++i) {
    float h0 = acc[i][0] + bv.x, h1 = acc[i][1] + bv.y;
    float h2 = acc[i][2] + bv.z, h3 = acc[i][3] + bv.w;
    float s = h0 * h0 + h1 * h1 + h2 * h2 + h3 * h3;
    s += __shfl_xor(s, 1, 64);
    s += __shfl_xor(s, 2, 64);
    s += __shfl_xor(s, 4, 64);
    s += __shfl_xor(s, 8, 64);
    float r = 1.0f / fmaxf(sqrtf(s), 1e-12f);
    int node = nodeBase + tn * 4 + i;
    if (node < N) {
      float o0 = h0 * r, o1 = h1 * r, o2 = h2 * r, o3 = h3 * r;
      float4 o = {o0, o1, o2, o3};
      *(float4*)(H + (size_t)node * WH + tc * 4) = o;
      int t = nt[node];
      int b = t * WH + tc * 4;
      atomicAdd(&ls[b + 0], o0);
      atomicAdd(&ls[b + 1], o1);
      atomicAdd(&ls[b + 2], o2);
      atomicAdd(&ls[b + 3], o3);
      atomicAdd(&ls2[b + 0], o0 * o0);
      atomicAdd(&ls2[b + 1], o1 * o1);
      atomicAdd(&ls2[b + 2], o2 * o2);
      atomicAdd(&ls2[b + 3], o3 * o3);
      if (tc == 0) atomicAdd(&lc[t], 1.0f);
    }
  }
  __syncthreads();
  psum[(size_t)blockIdx.x * 256 + tid] = ls[tid];
  psq[(size_t)blockIdx.x * 256 + tid] = ls2[tid];
  if (tid < TT) pcnt[(size_t)blockIdx.x * TT + tid] = lc[tid];
}

__global__ __launch_bounds__(256) void k_reduce_stats(const float* __restrict__ psum,
                                                      const float* __restrict__ psq,
                                                      const float* __restrict__ pcnt,
                                                      float* __restrict__ mean,
                                                      float* __restrict__ stdv,
                                                      float* __restrict__ counts, int NB) {
  __shared__ float c[TT];
  if (threadIdx.x < TT) {
    float s = 0.0f;
    for (int b = 0; b < NB; ++b) s += pcnt[(size_t)b * TT + threadIdx.x];
    counts[threadIdx.x] = s;
    c[threadIdx.x] = s;
  }
  __syncthreads();
  float s = 0.0f, q = 0.0f;
  for (int b = 0; b < NB; ++b) {
    s += psum[(size_t)b * 256 + threadIdx.x];
    q += psq[(size_t)b * 256 + threadIdx.x];
  }
  float n = c[threadIdx.x >> 6];
  float m = s / n;
  mean[threadIdx.x] = m;
  stdv[threadIdx.x] = (q - s * s / n) / sqrtf(n - 1.0f);
}

// tilde = (H-mean)/std -> bf16 only; LDS-private histogram -> partial dump
__global__ __launch_bounds__(256) void k_tilde_hist(const float* __restrict__ H,
                                                    const int* __restrict__ nt,
                                                    const float* __restrict__ mean,
                                                    const float* __restrict__ stdv,
                                                    ushortT* __restrict__ tb,
                                                    unsigned* __restrict__ pe, int NW) {
  __shared__ unsigned hist[BINS];
  for (int b = threadIdx.x; b < BINS; b += 256) hist[b] = 0;
  __syncthreads();
  for (int i = blockIdx.x * 256 + threadIdx.x; i < NW; i += HG * 256) {
    int nn = i >> 6, d = i & 63;
    int t = nt[nn];
    float v = (H[i] - mean[t * WH + d]) / stdv[t * WH + d];
    unsigned u = __float_as_uint(v);
    tb[i] = (ushortT)((u + 0x7FFFu + ((u >> 16) & 1u)) >> 16);
    int b = (int)((v + 8.0f) * BIN_SCALE);
    b = min(max(b, 0), BINS - 1);
    atomicAdd(&hist[b], 1u);
  }
  __syncthreads();
  for (int b = threadIdx.x; b < BINS; b += 256)
    pe[(size_t)blockIdx.x * BINS + b] = hist[b];
}

__global__ __launch_bounds__(256) void k_histG(const float* __restrict__ g,
                                               unsigned* __restrict__ pg, int M) {
  __shared__ unsigned hist[BINS];
  for (int b = threadIdx.x; b < BINS; b += 256) hist[b] = 0;
  __syncthreads();
  for (int i = blockIdx.x * 256 + threadIdx.x; i < M; i += HG * 256) {
    float v = g[i];
    int b = (int)((v + 8.0f) * BIN_SCALE);
    b = min(max(b, 0), BINS - 1);
    atomicAdd(&hist[b], 1u);
  }
  __syncthreads();
  for (int b = threadIdx.x; b < BINS; b += 256)
    pg[(size_t)blockIdx.x * BINS + b] = hist[b];
}

__global__ __launch_bounds__(256) void k_diff(const unsigned* __restrict__ pg,
                                              const unsigned* __restrict__ pe,
                                              int* __restrict__ diff) {
  int b = blockIdx.x * 256 + threadIdx.x;
  int s = 0;
  for (int p = 0; p < HG; ++p)
    s += (int)pg[(size_t)p * BINS + b] - (int)pe[(size_t)p * BINS + b];
  diff[b] = s;
}

__global__ __launch_bounds__(1024) void k_wass(const int* __restrict__ diff,
                                               float* __restrict__ out, int M, int NW) {
  int tid = threadIdx.x;
  int lo = tid * (BINS / 1024);
  int d[BINS / 1024];
  int s = 0;
#pragma unroll
  for (int i = 0; i < BINS / 1024; ++i) {
    d[i] = diff[lo + i];
    s += d[i];
  }
  __shared__ int sc[1024];
  sc[tid] = s;
  __syncthreads();
  for (int st = 1; st < 1024; st <<= 1) {
    int v = (tid >= st) ? sc[tid - st] : 0;
    __syncthreads();
    sc[tid] += v;
    __syncthreads();
  }
  int run = sc[tid] - s;
  long long a = 0;
#pragma unroll
  for (int i = 0; i < BINS / 1024; ++i) {
    run += d[i];
    a += (long long)(run < 0 ? -run : run);
  }
  __shared__ long long rd[1024];
  rd[tid] = a;
  __syncthreads();
  for (int st = 512; st > 0; st >>= 1) {
    if (tid < st) rd[tid] += rd[tid + st];
    __syncthreads();
  }
  if (tid == 0) out[NW] = (float)((double)rd[0] * (1.0 / (double)BIN_SCALE) / (double)M);
}

// ---------- CSR build ----------
__global__ __launch_bounds__(256) void k_degi(const int* __restrict__ dst,
                                              unsigned* __restrict__ degi, int E) {
  int e = blockIdx.x * 256 + threadIdx.x;
  if (e < E) atomicAdd(&degi[dst[e]], 1u);
}

// decoupled 3-pass exclusive scan (SB blocks)
__global__ __launch_bounds__(256) void k_scan_p1(const unsigned* __restrict__ in,
                                                 unsigned* __restrict__ bsum, int L) {
  int chunk = (L + SB - 1) / SB;
  int lo = blockIdx.x * chunk, hi = min(lo + chunk, L);
  unsigned s = 0;
  for (int i = lo + threadIdx.x; i < hi; i += 256) s += in[i];
  __shared__ unsigned sd[256];
  sd[threadIdx.x] = s;
  __syncthreads();
  for (int st = 128; st > 0; st >>= 1) {
    if (threadIdx.x < st) sd[threadIdx.x] += sd[threadIdx.x + st];
    __syncthreads();
  }
  if (threadIdx.x == 0) bsum[blockIdx.x] = sd[0];
}
__global__ __launch_bounds__(256) void k_scan_p2(unsigned* __restrict__ bsum) {
  int tid = threadIdx.x;
  __shared__ unsigned ts[SB];
  unsigned v = bsum[tid];
  ts[tid] = v;
  __syncthreads();
  for (int st = 1; st < SB; st <<= 1) {
    unsigned u = (tid >= st) ? ts[tid - st] : 0u;
    __syncthreads();
    ts[tid] += u;
    __syncthreads();
  }
  bsum[tid] = ts[tid] - v;  // exclusive
}
__global__ __launch_bounds__(256) void k_scan_p3(const unsigned* __restrict__ in,
                                                 const unsigned* __restrict__ bsum,
                                                 unsigned* __restrict__ outp, int L) {
  int chunk = (L + SB - 1) / SB;
  int lo = blockIdx.x * chunk, hi = min(lo + chunk, L);
  int per = (chunk + 255) / 256;
  int tlo = lo + threadIdx.x * per, thi = min(tlo + per, hi);
  unsigned s = 0;
  for (int i = tlo; i < thi; ++i) s += in[i];
  __shared__ unsigned ts[256];
  ts[threadIdx.x] = s;
  __syncthreads();
  for (int st = 1; st < 256; st <<= 1) {
    unsigned u = (threadIdx.x >= st) ? ts[threadIdx.x - st] : 0u;
    __syncthreads();
    ts[threadIdx.x] += u;
    __syncthreads();
  }
  unsigned run = bsum[blockIdx.x] + ts[threadIdx.x] - s;
  for (int i = tlo; i < thi; ++i) {
    outp[i] = run;
    run += in[i];
  }
}

__global__ __launch_bounds__(256) void k_build(const int* __restrict__ src,
                                               const int* __restrict__ dst,
                                               const unsigned* __restrict__ off,
                                               unsigned* __restrict__ cur,
                                               unsigned* __restrict__ esrc, int E) {
  int e = blockIdx.x * 256 + threadIdx.x;
  if (e >= E) return;
  int t = dst[e];
  unsigned p = off[t] + atomicAdd(&cur[t], 1u);
  esrc[p] = (unsigned)src[e];
}

// ---------- diffusion hop (bf16 Z, bf16 restart) ----------
__global__ __launch_bounds__(256) void k_spmm(const unsigned* __restrict__ off,
                                              const unsigned* __restrict__ degi,
                                              const unsigned* __restrict__ esrc,
                                              const ushortT* __restrict__ Zb,
                                              const ushortT* __restrict__ Tb,
                                              ushortT* __restrict__ Zn, int N) {
  int wv = threadIdx.x >> 6, lane = threadIdx.x & 63;
  int n = blockIdx.x * 4 + wv;
  if (n >= N) return;
  int g = lane >> 3, c = lane & 7;
  unsigned st = off[n], dg = degi[n];
  float a[8] = {};
  for (unsigned e = g; e < dg; e += 8) {
    unsigned s = esrc[st + e];
    uint4 v = *((const uint4*)(Zb + (size_t)s * WH) + c);
    a[0] += bf_lo(v.x); a[1] += bf_hi(v.x);
    a[2] += bf_lo(v.y); a[3] += bf_hi(v.y);
    a[4] += bf_lo(v.z); a[5] += bf_hi(v.z);
    a[6] += bf_lo(v.w); a[7] += bf_hi(v.w);
  }
#pragma unroll
  for (int m = 8; m <= 32; m <<= 1) {
#pragma unroll
    for (int j = 0; j < 8; ++j) a[j] += __shfl_xor(a[j], m, 64);
  }
  if (g == 0) {
    float wn = (1.0f - ALPHA_C) / fmaxf((float)dg, 1.0f);
    uint4 tv = *((const uint4*)(Tb + (size_t)n * WH) + c);
    uint4 p;
    p.x = pack_bf16(wn * a[0] + ALPHA_C * bf_lo(tv.x), wn * a[1] + ALPHA_C * bf_hi(tv.x));
    p.y = pack_bf16(wn * a[2] + ALPHA_C * bf_lo(tv.y), wn * a[3] + ALPHA_C * bf_hi(tv.y));
    p.z = pack_bf16(wn * a[4] + ALPHA_C * bf_lo(tv.z), wn * a[5] + ALPHA_C * bf_hi(tv.z));
    p.w = pack_bf16(wn * a[6] + ALPHA_C * bf_lo(tv.w), wn * a[7] + ALPHA_C * bf_hi(tv.w));
    *((uint4*)(Zn + (size_t)n * WH) + c) = p;
  }
}

// ---------- last hop fused with denorm + row-L2 -> out ----------
__global__ __launch_bounds__(256) void k_spmm_final(const unsigned* __restrict__ off,
                                                    const unsigned* __restrict__ degi,
                                                    const unsigned* __restrict__ esrc,
                                                    const ushortT* __restrict__ Zb,
                                                    const ushortT* __restrict__ Tb,
                                                    const int* __restrict__ nt,
                                                    const float* __restrict__ mean,
                                                    const float* __restrict__ stdv,
                                                    float* __restrict__ out, int N) {
  int wv = threadIdx.x >> 6, lane = threadIdx.x & 63;
  int n = blockIdx.x * 4 + wv;
  if (n >= N) return;
  int g = lane >> 3, c = lane & 7;
  unsigned st = off[n], dg = degi[n];
  float a[8] = {};
  for (unsigned e = g; e < dg; e += 8) {
    unsigned s = esrc[st + e];
    uint4 v = *((const uint4*)(Zb + (size_t)s * WH) + c);
    a[0] += bf_lo(v.x); a[1] += bf_hi(v.x);
    a[2] += bf_lo(v.y); a[3] += bf_hi(v.y);
    a[4] += bf_lo(v.z); a[5] += bf_hi(v.z);
    a[6] += bf_lo(v.w); a[7] += bf_hi(v.w);
  }
#pragma unroll
  for (int m = 8; m <= 32; m <<= 1) {
#pragma unroll
    for (int j = 0; j < 8; ++j) a[j] += __shfl_xor(a[j], m, 64);
  }
  // every lane now holds full sums for its 8 columns [c*8, c*8+8)
  float wn = (1.0f - ALPHA_C) / fmaxf((float)dg, 1.0f);
  uint4 tv = *((const uint4*)(Tb + (size_t)n * WH) + c);
  float t[8] = {bf_lo(tv.x), bf_hi(tv.x), bf_lo(tv.y), bf_hi(tv.y),
                bf_lo(tv.z), bf_hi(tv.z), bf_lo(tv.w), bf_hi(tv.w)};
  int ty = nt[n];
  int base = ty * WH + c * 8;
  float4 sd0 = *(const float4*)(stdv + base), sd1 = *(const float4*)(stdv + base + 4);
  float4 mn0 = *(const float4*)(mean + base), mn1 = *(const float4*)(mean + base + 4);
  float z[8];
  z[0] = (wn * a[0] + ALPHA_C * t[0]) * sd0.x + mn0.x;
  z[1] = (wn * a[1] + ALPHA_C * t[1]) * sd0.y + mn0.y;
  z[2] = (wn * a[2] + ALPHA_C * t[2]) * sd0.z + mn0.z;
  z[3] = (wn * a[3] + ALPHA_C * t[3]) * sd0.w + mn0.w;
  z[4] = (wn * a[4] + ALPHA_C * t[4]) * sd1.x + mn1.x;
  z[5] = (wn * a[5] + ALPHA_C * t[5]) * sd1.y + mn1.y;
  z[6] = (wn * a[6] + ALPHA_C * t[6]) * sd1.z + mn1.z;
  z[7] = (wn * a[7] + ALPHA_C * t[7]) * sd1.w + mn1.w;
  float s = 0.0f;
#pragma unroll
  for (int j = 0; j < 8; ++j) s += z[j] * z[j];
  s += __shfl_xor(s, 1, 64);
  s += __shfl_xor(s, 2, 64);
  s += __shfl_xor(s, 4, 64);
  float r = 1.0f / fmaxf(sqrtf(s), 1e-12f);
  if (g == 0) {
    float4 o0 = {z[0] * r, z[1] * r, z[2] * r, z[3] * r};
    float4 o1 = {z[4] * r, z[5] * r, z[6] * r, z[7] * r};
    float4* Or = (float4*)(out + (size_t)n * WH);
    Or[c * 2] = o0;
    Or[c * 2 + 1] = o1;
  }
}

extern "C" void kernel_launch(void* const* d_in, const int* in_sizes, int n_in,
                              void* d_out, int out_size, void* d_ws, size_t ws_size,
                              hipStream_t stream) {
  const float* X = (const float*)d_in[0];
  const float* W = (const float*)d_in[1];
  const float* bias = (const float*)d_in[2];
  const float* g = (const float*)d_in[3];
  const int* ei = (const int*)d_in[4];
  const int* nt = (const int*)d_in[5];

  const int N = in_sizes[5];
  const int E = in_sizes[4] / 2;
  const int M = in_sizes[3];  // N * WH
  const int NW = N * WH;
  const int NBLK = (N + BN - 1) / BN;
  const int* srcp = ei;
  const int* dstp = ei + E;

  char* w = (char*)d_ws;
  size_t o = 0;
  auto alloc = [&](size_t bytes) {
    size_t r = o;
    o += (bytes + 255) & ~(size_t)255;
    return r;
  };
  size_t off_stats = alloc(4096);  // counts@0, mean@256, std@1280
  size_t off_psum  = alloc((size_t)NBLK * 256 * 4);
  size_t off_psq   = alloc((size_t)NBLK * 256 * 4);
  size_t off_pcnt  = alloc((size_t)NBLK * TT * 4);
  size_t off_diff  = alloc((size_t)BINS * 4);
  size_t off_bsum  = alloc((size_t)SB * 4);
  size_t off_degi  = alloc((size_t)N * 4);  // memset region start
  size_t off_cur   = alloc((size_t)N * 4);  // memset region end (256B-aligned slot!)
  size_t off_off   = alloc((size_t)N * 4);
  size_t off_esrc  = alloc((size_t)E * 4);
  size_t off_H     = alloc((size_t)NW * 4);
  size_t off_tbf   = alloc((size_t)NW * 2);  // bf16 tilde (restart + hop-0 source)
  size_t off_bufA  = alloc((size_t)NW * 4);  // partial hists alias; later bf16 Z ping
  size_t off_bufB  = alloc((size_t)NW * 4);  // partial hists alias; later bf16 Z pong

  float* counts = (float*)(w + off_stats + 0);
  float* mean   = (float*)(w + off_stats + 256);
  float* stdv   = (float*)(w + off_stats + 1280);
  float* psum   = (float*)(w + off_psum);
  float* psq    = (float*)(w + off_psq);
  float* pcnt   = (float*)(w + off_pcnt);
  int* diff     = (int*)(w + off_diff);
  unsigned* bsum = (unsigned*)(w + off_bsum);
  unsigned* degi = (unsigned*)(w + off_degi);
  unsigned* cur  = (unsigned*)(w + off_cur);
  unsigned* offp = (unsigned*)(w + off_off);
  unsigned* esrc = (unsigned*)(w + off_esrc);
  float* H       = (float*)(w + off_H);
  ushortT* tbf   = (ushortT*)(w + off_tbf);
  unsigned* pg   = (unsigned*)(w + off_bufA);
  unsigned* pe   = (unsigned*)(w + off_bufB);
  ushortT* ZA    = (ushortT*)(w + off_bufA);
  ushortT* ZB    = (ushortT*)(w + off_bufB);
  float* out = (float*)d_out;

  // zero degree+cursor; span covers the alignment pad between slots.
  hipMemsetAsync(w + off_degi, 0, off_cur - off_degi + (size_t)N * 4, stream);

  // 1) encode + L2 norm -> H, with fused per-type stats partials
  k_encode<<<NBLK, 256, 0, stream>>>(X, W, bias, nt, H, psum, psq, pcnt, N);
  k_reduce_stats<<<1, 256, 0, stream>>>(psum, psq, pcnt, mean, stdv, counts, NBLK);

  // 2) tilde -> bf16 + LDS histograms
  k_tilde_hist<<<HG, 256, 0, stream>>>(H, nt, mean, stdv, tbf, pe, NW);
  k_histG<<<HG, 256, 0, stream>>>(g, pg, M);

  // 3) W1 = (delta/M) * sum_b |prefix(cg-ce)|
  k_diff<<<BINS / 256, 256, 0, stream>>>(pg, pe, diff);
  k_wass<<<1, 1024, 0, stream>>>(diff, out, M, NW);

  // 4) CSR build with decoupled scan
  k_degi<<<(E + 255) / 256, 256, 0, stream>>>(dstp, degi, E);
  k_scan_p1<<<SB, 256, 0, stream>>>(degi, bsum, N);
  k_scan_p2<<<1, SB, 0, stream>>>(bsum);
  k_scan_p3<<<SB, 256, 0, stream>>>(degi, bsum, offp, N);
  k_build<<<(E + 255) / 256, 256, 0, stream>>>(srcp, dstp, offp, cur, esrc, E);

  // 5) K=10 hops: 9 ping-pong + 1 fused with epilogue (partial hists dead now)
  const ushortT* Zc = tbf;
  for (int k = 0; k < 9; ++k) {
    ushortT* Zn = (k & 1) ? ZB : ZA;
    k_spmm<<<(N + 3) / 4, 256, 0, stream>>>(offp, degi, esrc, Zc, tbf, Zn, N);
    Zc = Zn;
  }
  k_spmm_final<<<(N + 3) / 4, 256, 0, stream>>>(offp, degi, esrc, Zc, tbf, nt, mean, stdv,
                                                out, N);
}